// Round 1
// baseline (6989.211 us; speedup 1.0000x reference)
//
#include <hip/hip_runtime.h>
#include <hip/hip_bf16.h>
#include <math.h>

namespace {
constexpr int TT   = 32;    // block_size
constexpr int EMB  = 256;
constexpr int HD   = 128;   // total head dim
constexpr int NHEAD = 8;
constexpr int DHEAD = 16;
constexpr int FF   = 1024;
constexpr float EPSV = 1e-5f;

// LN over rows of a [32][256] LDS tile. 8 threads per row (tid/8 = row).
__device__ __forceinline__ void layernorm_tile(
    const float (*in)[EMB], float (*out_)[EMB],
    const float* __restrict__ g, const float* __restrict__ bb, int tid)
{
    int r = tid >> 3, sub = tid & 7;
    float s = 0.f, ss = 0.f;
    #pragma unroll
    for (int j = 0; j < EMB/8; ++j) {
        float v = in[r][sub + 8*j];
        s += v; ss += v*v;
    }
    #pragma unroll
    for (int w = 1; w < 8; w <<= 1) {          // reduce within the 8-lane row group
        s  += __shfl_xor(s, w, 64);
        ss += __shfl_xor(ss, w, 64);
    }
    float mu  = s * (1.f/EMB);
    float var = ss * (1.f/EMB) - mu*mu;
    float inv = rsqrtf(var + EPSV);
    #pragma unroll
    for (int j = 0; j < EMB/8; ++j) {
        int c = sub + 8*j;
        out_[r][c] = (in[r][c] - mu) * inv * g[c] + bb[c];
    }
}
} // namespace

// One block per sequence b. 256 threads. Everything fused, fp32, no workspace.
__global__ __launch_bounds__(256) void attn_block_fused(
    const float* __restrict__ X,
    const float* __restrict__ ln_g, const float* __restrict__ ln_b,
    const float* __restrict__ Wq, const float* __restrict__ bq,
    const float* __restrict__ Wk, const float* __restrict__ bk,
    const float* __restrict__ Wv, const float* __restrict__ bv,
    const float* __restrict__ Wo, const float* __restrict__ bo,
    const float* __restrict__ W1, const float* __restrict__ b1,
    const float* __restrict__ W2, const float* __restrict__ b2,
    float* __restrict__ out)
{
    __shared__ float xs[TT][EMB];     // X, later X1 (post residual-1)  32KB
    __shared__ float hs[TT][EMB];     // h (LN1), later h2 (LN2)        32KB
    __shared__ float qkv[3*TT*HD];    // Q,K,V; Q->ctx; later F chunk   48KB

    const int tid = threadIdx.x;
    const int b = blockIdx.x;
    const float* Xb = X + (size_t)b * (TT*EMB);

    // ---- P0: load X tile (coalesced float4) ----
    {
        const float4* src = (const float4*)Xb;
        float4* dst = (float4*)&xs[0][0];
        #pragma unroll
        for (int i = 0; i < (TT*EMB/4)/256; ++i)
            dst[tid + 256*i] = src[tid + 256*i];
    }
    __syncthreads();

    // ---- P1: LN1  xs -> hs ----
    layernorm_tile(xs, hs, ln_g, ln_b, tid);
    __syncthreads();

    // ---- P2: QKV = h @ W{q,k,v} + b.   thread tile: 4 rows x 4 cols ----
    {
        const int rg = tid >> 5;         // 0..7  -> rows rg*4..rg*4+3
        const int cg = tid & 31;         // cols cg*4..cg*4+3
        const float* Ws[3] = {Wq, Wk, Wv};
        const float* bs[3] = {bq, bk, bv};
        #pragma unroll
        for (int m = 0; m < 3; ++m) {
            float acc[4][4] = {};
            const float* W = Ws[m];
            #pragma unroll 4
            for (int k = 0; k < EMB; ++k) {
                float4 w = *(const float4*)&W[k*HD + cg*4];
                float wv[4] = {w.x, w.y, w.z, w.w};
                #pragma unroll
                for (int i = 0; i < 4; ++i) {
                    float hv = hs[rg*4+i][k];
                    #pragma unroll
                    for (int j = 0; j < 4; ++j) acc[i][j] += hv * wv[j];
                }
            }
            const float* bias = bs[m];
            #pragma unroll
            for (int i = 0; i < 4; ++i)
                #pragma unroll
                for (int j = 0; j < 4; ++j)
                    qkv[m*TT*HD + (rg*4+i)*HD + cg*4+j] = acc[i][j] + bias[cg*4+j];
        }
    }
    __syncthreads();

    // ---- P3: attention. thread = (head, q-row). scores kept in registers ----
    {
        const int hd = tid >> 5;     // 0..7
        const int q  = tid & 31;     // 0..31
        const float* Q = &qkv[0*TT*HD];
        const float* K = &qkv[1*TT*HD];
        const float* V = &qkv[2*TT*HD];
        float qr[DHEAD];
        #pragma unroll
        for (int d = 0; d < DHEAD; ++d) qr[d] = Q[q*HD + hd*DHEAD + d];

        float p[TT];
        float mmax = -1e30f;
        #pragma unroll
        for (int k = 0; k < TT; ++k) {
            float s = 0.f;
            #pragma unroll
            for (int d = 0; d < DHEAD; ++d) s += qr[d] * K[k*HD + hd*DHEAD + d];
            s *= 0.25f;                       // 1/sqrt(DH); applied only to kept entries
            p[k] = s;
            if (k <= q && s > mmax) mmax = s;
        }
        float denom = 0.f;
        #pragma unroll
        for (int k = 0; k < TT; ++k) {
            float e = (k <= q) ? __expf(p[k] - mmax) : 0.f;   // causal mask
            p[k] = e; denom += e;
        }
        const float rden = 1.f / denom;
        // ctx overwrites this thread's own Q slots (no other thread reads them)
        #pragma unroll
        for (int d = 0; d < DHEAD; ++d) {
            float c = 0.f;
            #pragma unroll
            for (int k = 0; k < TT; ++k) c += p[k] * V[k*HD + hd*DHEAD + d];
            qkv[0*TT*HD + q*HD + hd*DHEAD + d] = c * rden;
        }
    }
    __syncthreads();

    // ---- P4: X1 = ctx @ Wo + bo + X.   thread tile: 4 rows x 8 cols ----
    {
        const int rg = tid >> 5;
        const int cg = tid & 31;          // cols cg*8..cg*8+7
        const float* C = &qkv[0];
        float acc[4][8] = {};
        #pragma unroll 4
        for (int k = 0; k < HD; ++k) {
            float4 w0 = *(const float4*)&Wo[k*EMB + cg*8];
            float4 w1 = *(const float4*)&Wo[k*EMB + cg*8 + 4];
            float wv[8] = {w0.x,w0.y,w0.z,w0.w,w1.x,w1.y,w1.z,w1.w};
            #pragma unroll
            for (int i = 0; i < 4; ++i) {
                float cv = C[(rg*4+i)*HD + k];
                #pragma unroll
                for (int j = 0; j < 8; ++j) acc[i][j] += cv * wv[j];
            }
        }
        #pragma unroll
        for (int i = 0; i < 4; ++i)
            #pragma unroll
            for (int j = 0; j < 8; ++j) {
                int r = rg*4+i, c = cg*8+j;
                xs[r][c] = acc[i][j] + bo[c] + xs[r][c];     // residual 1, in place
            }
    }
    __syncthreads();

    // ---- P5: LN2  xs(X1) -> hs(h2), shared LN params ----
    layernorm_tile(xs, hs, ln_g, ln_b, tid);
    __syncthreads();

    // ---- P6: FFN fused: out = relu(h2@W1+b1)@W2 + b2 + X1 ----
    {
        const int rg = tid >> 5;
        const int cg = tid & 31;
        float* Fc = &qkv[0];              // [32][128] chunk buffer
        float oacc[4][8] = {};
        for (int ff0 = 0; ff0 < FF; ff0 += 128) {
            // FFN1 chunk: Fc = relu(h2 @ W1[:, ff0:ff0+128] + b1)   (4x4 tile)
            float facc[4][4] = {};
            #pragma unroll 4
            for (int k = 0; k < EMB; ++k) {
                float4 w = *(const float4*)&W1[k*FF + ff0 + cg*4];
                float wv[4] = {w.x, w.y, w.z, w.w};
                #pragma unroll
                for (int i = 0; i < 4; ++i) {
                    float hv = hs[rg*4+i][k];
                    #pragma unroll
                    for (int j = 0; j < 4; ++j) facc[i][j] += hv * wv[j];
                }
            }
            __syncthreads();              // prev chunk's FFN2 reads done
            #pragma unroll
            for (int i = 0; i < 4; ++i)
                #pragma unroll
                for (int j = 0; j < 4; ++j)
                    Fc[(rg*4+i)*128 + cg*4+j] =
                        fmaxf(facc[i][j] + b1[ff0 + cg*4+j], 0.f);
            __syncthreads();
            // FFN2 accumulate: oacc += Fc @ W2[ff0:ff0+128, :]      (4x8 tile)
            #pragma unroll 2
            for (int k = 0; k < 128; ++k) {
                float4 w0 = *(const float4*)&W2[(ff0+k)*EMB + cg*8];
                float4 w1 = *(const float4*)&W2[(ff0+k)*EMB + cg*8 + 4];
                float wv[8] = {w0.x,w0.y,w0.z,w0.w,w1.x,w1.y,w1.z,w1.w};
                #pragma unroll
                for (int i = 0; i < 4; ++i) {
                    float fv = Fc[(rg*4+i)*128 + k];
                    #pragma unroll
                    for (int j = 0; j < 8; ++j) oacc[i][j] += fv * wv[j];
                }
            }
        }
        // epilogue: + b2 + X1, store
        float* outb = out + (size_t)b * (TT*EMB);
        #pragma unroll
        for (int i = 0; i < 4; ++i) {
            int r = rg*4+i;
            float4 o0, o1;
            float* po = (float*)&o0;
            #pragma unroll
            for (int j = 0; j < 8; ++j) {
                int c = cg*8+j;
                ((float*)&o0)[0]; // no-op to keep struct simple
                po[j < 4 ? j : j] = 0.f; // placeholder, overwritten below
            }
            float tmp[8];
            #pragma unroll
            for (int j = 0; j < 8; ++j) {
                int c = cg*8+j;
                tmp[j] = oacc[i][j] + b2[c] + xs[r][c];
            }
            o0 = make_float4(tmp[0], tmp[1], tmp[2], tmp[3]);
            o1 = make_float4(tmp[4], tmp[5], tmp[6], tmp[7]);
            *(float4*)&outb[r*EMB + cg*8]     = o0;
            *(float4*)&outb[r*EMB + cg*8 + 4] = o1;
        }
    }
}

extern "C" void kernel_launch(void* const* d_in, const int* in_sizes, int n_in,
                              void* d_out, int out_size, void* d_ws, size_t ws_size,
                              hipStream_t stream) {
    const float* X    = (const float*)d_in[0];
    const float* ln_g = (const float*)d_in[1];
    const float* ln_b = (const float*)d_in[2];
    const float* Wq   = (const float*)d_in[3];
    const float* bq   = (const float*)d_in[4];
    const float* Wk   = (const float*)d_in[5];
    const float* bk   = (const float*)d_in[6];
    const float* Wv   = (const float*)d_in[7];
    const float* bv   = (const float*)d_in[8];
    const float* Wo   = (const float*)d_in[9];
    const float* bo   = (const float*)d_in[10];
    const float* W1   = (const float*)d_in[11];
    const float* b1   = (const float*)d_in[12];
    const float* W2   = (const float*)d_in[13];
    const float* b2   = (const float*)d_in[14];
    float* O = (float*)d_out;

    const int nblocks = 4096;   // B
    attn_block_fused<<<nblocks, 256, 0, stream>>>(
        X, ln_g, ln_b, Wq, bq, Wk, bk, Wv, bv, Wo, bo, W1, b1, W2, b2, O);
}

// Round 2
// 860.453 us; speedup vs baseline: 8.1227x; 8.1227x over previous
//
#include <hip/hip_runtime.h>
#include <math.h>

typedef __attribute__((ext_vector_type(8))) __bf16 bf16x8;
typedef __attribute__((ext_vector_type(8))) unsigned short u16x8;
typedef __attribute__((ext_vector_type(4))) float f32x4;

namespace {
constexpr int TT  = 32;
constexpr int EMB = 256;
constexpr int HD  = 128;
constexpr int FF  = 1024;
constexpr float EPSV = 1e-5f;

// ws layout (ushort elements):
//   WTqkv [384][256] @ 0        (rows: 0-127 Q cols, 128-255 K cols, 256-383 V cols)
//   WTo   [256][128] @ 98304
//   WT1   [1024][256]@ 131072
//   WT2   [256][1024]@ 393216   — total 655360 elems = 1.31 MB
constexpr int WS_QKV = 0;
constexpr int WS_O   = 98304;
constexpr int WS_1   = 131072;
constexpr int WS_2   = 393216;

__device__ __forceinline__ unsigned short f32_to_bf16(float f) {
    unsigned int u = __builtin_bit_cast(unsigned int, f);
    u += 0x7FFFu + ((u >> 16) & 1u);           // RNE; inputs finite
    return (unsigned short)(u >> 16);
}
__device__ __forceinline__ float bf16_to_f32(unsigned short h) {
    return __builtin_bit_cast(float, ((unsigned int)h) << 16);
}
__device__ __forceinline__ f32x4 mfma16(u16x8 a, u16x8 b, f32x4 c) {
    return __builtin_amdgcn_mfma_f32_16x16x32_bf16(
        __builtin_bit_cast(bf16x8, a), __builtin_bit_cast(bf16x8, b), c, 0, 0, 0);
}
// swizzled LDS A-fragment read: row-major bf16 tile, stride rowBytes.
// lane supplies row = .. + (lane&15), k0 = base_k + (lane>>4)*8 (8 contiguous bf16 = 16B)
__device__ __forceinline__ u16x8 ldsA(const unsigned short* base, int row, int k0, int rowBytes) {
    int byte = row * rowBytes + k0 * 2;
    byte ^= (row & 7) << 4;                    // bank-conflict swizzle (G4)
    return *(const u16x8*)((const char*)base + byte);
}
// B-fragment straight from global (L2-resident W^T, [N][K] bf16 row-major)
__device__ __forceinline__ u16x8 ldgB(const unsigned short* WT, int K, int nt, int kk, int lane) {
    const unsigned short* p = WT + (size_t)(nt * 16 + (lane & 15)) * K + kk * 32 + (lane >> 4) * 8;
    return *(const u16x8*)p;
}

// LN of fp32 [32][256] LDS tile -> swizzled bf16 LDS tile (rowBytes=512)
__device__ __forceinline__ void ln_bf16(const float (*in)[EMB], unsigned short* outb,
                                        const float* __restrict__ g, const float* __restrict__ bb,
                                        int tid) {
    const int r = tid >> 3, sub = tid & 7;
    float s = 0.f, ss = 0.f;
    #pragma unroll
    for (int j = 0; j < 8; ++j) {
        float4 v = *(const float4*)&in[r][sub * 32 + 4 * j];
        s  += (v.x + v.y) + (v.z + v.w);
        ss += (v.x * v.x + v.y * v.y) + (v.z * v.z + v.w * v.w);
    }
    #pragma unroll
    for (int w = 1; w < 8; w <<= 1) { s += __shfl_xor(s, w, 64); ss += __shfl_xor(ss, w, 64); }
    float mu  = s * (1.f / EMB);
    float inv = rsqrtf(fmaxf(ss * (1.f / EMB) - mu * mu, 0.f) + EPSV);
    #pragma unroll
    for (int cc = 0; cc < 4; ++cc) {
        int c0 = sub * 32 + cc * 8;
        u16x8 pk;
        #pragma unroll
        for (int j = 0; j < 8; ++j)
            pk[j] = f32_to_bf16((in[r][c0 + j] - mu) * inv * g[c0 + j] + bb[c0 + j]);
        int byte = (r * 512 + c0 * 2) ^ ((r & 7) << 4);
        *(u16x8*)((char*)outb + byte) = pk;
    }
}
} // namespace

// one-shot weight transpose + fp32->bf16 into workspace (runs every launch, ~1.3MB)
__global__ __launch_bounds__(256) void wconv(
    const float* __restrict__ Wq, const float* __restrict__ Wk, const float* __restrict__ Wv,
    const float* __restrict__ Wo, const float* __restrict__ W1, const float* __restrict__ W2,
    unsigned short* __restrict__ ws) {
    int idx = blockIdx.x * 256 + threadIdx.x;   // 0..655359
    float v;
    if (idx < 98304) {                 // WTqkv[n][k] = W{q,k,v}[k][n&127]
        int n = idx >> 8, k = idx & 255;
        const float* W = (n < 128) ? Wq : ((n < 256) ? Wk : Wv);
        v = W[k * HD + (n & 127)];
    } else if (idx < 393216 && idx >= 131072) { // WT1[n][k] = W1[k][n]
        int j = idx - 131072; int n = j >> 8, k = j & 255;
        v = W1[k * FF + n];
    } else if (idx < 131072) {         // WTo[n][k] = Wo[k][n]
        int j = idx - 98304; int n = j >> 7, k = j & 127;
        v = Wo[k * EMB + n];
    } else {                           // WT2[n][k] = W2[k][n]
        int j = idx - 393216; int n = j >> 10, k = j & 1023;
        v = W2[k * EMB + n];
    }
    ws[idx] = f32_to_bf16(v);
}

// one block per sequence; 4 waves; all GEMMs on MFMA, weights from L2 via ws
__global__ __launch_bounds__(256, 2) void attn_block_mfma(
    const float* __restrict__ X, const float* __restrict__ ln_g, const float* __restrict__ ln_b,
    const float* __restrict__ bq, const float* __restrict__ bk, const float* __restrict__ bv,
    const float* __restrict__ bo, const float* __restrict__ b1, const float* __restrict__ b2,
    const unsigned short* __restrict__ ws, float* __restrict__ out) {
    __shared__ float xs[TT][EMB];               // 32KB: X, then X1
    __shared__ unsigned short hb[TT * EMB];     // 16KB: h / h2 (swz, rb=512); [0,8KB) reused as ctx (swz, rb=256)
    __shared__ unsigned short qkvb[3 * TT * HD];// 24KB: Q,K,V plain; [0,16KB) reused as FFN chunk (swz, rb=512)

    const unsigned short* WTqkv = ws + WS_QKV;
    const unsigned short* WTo   = ws + WS_O;
    const unsigned short* WT1   = ws + WS_1;
    const unsigned short* WT2   = ws + WS_2;

    const int tid  = threadIdx.x;
    const int wv   = tid >> 6;
    const int lane = tid & 63;
    const int b    = blockIdx.x;
    const f32x4 Z  = {0.f, 0.f, 0.f, 0.f};
    const float* Xb = X + (size_t)b * (TT * EMB);

    // ---- P0: load X tile ----
    {
        const float4* src = (const float4*)Xb;
        float4* dst = (float4*)&xs[0][0];
        #pragma unroll
        for (int i = 0; i < 8; ++i) dst[tid + 256 * i] = src[tid + 256 * i];
    }
    __syncthreads();
    // ---- P1: LN1 ----
    ln_bf16(xs, hb, ln_g, ln_b, tid);
    __syncthreads();

    // ---- P2: QKV = h @ Wqkv + b  (24 n-tiles, 2 m-tiles, K=256) ----
    {
        u16x8 afr[2][8];
        #pragma unroll
        for (int m = 0; m < 2; ++m)
            #pragma unroll
            for (int kk = 0; kk < 8; ++kk)
                afr[m][kk] = ldsA(hb, m * 16 + (lane & 15), kk * 32 + (lane >> 4) * 8, 512);
        for (int nt = wv; nt < 24; nt += 4) {
            u16x8 bfr[8];
            #pragma unroll
            for (int kk = 0; kk < 8; ++kk) bfr[kk] = ldgB(WTqkv, 256, nt, kk, lane);
            f32x4 acc0 = Z, acc1 = Z;
            #pragma unroll
            for (int kk = 0; kk < 8; ++kk) {
                acc0 = mfma16(afr[0][kk], bfr[kk], acc0);
                acc1 = mfma16(afr[1][kk], bfr[kk], acc1);
            }
            int gcol = nt * 16 + (lane & 15);
            int mat = gcol >> 7, c = gcol & 127;
            const float* bias = (mat == 0) ? bq : ((mat == 1) ? bk : bv);
            float bcol = bias[c];
            #pragma unroll
            for (int reg = 0; reg < 4; ++reg) {
                int r0 = (lane >> 4) * 4 + reg;          // C/D map (m89)
                qkvb[mat * 4096 + r0 * 128 + c]        = f32_to_bf16(acc0[reg] + bcol);
                qkvb[mat * 4096 + (16 + r0) * 128 + c] = f32_to_bf16(acc1[reg] + bcol);
            }
        }
    }
    __syncthreads();

    // ---- P3: attention (VALU). thread=(head,q); K/V row reads broadcast ----
    {
        unsigned short* ctxb = hb;                       // overlay: h dead until LN2
        const int hd = tid >> 5, q = tid & 31;
        const unsigned short* Qr = &qkvb[q * 128 + hd * 16];
        float qreg[16];
        {
            u16x8 a = *(const u16x8*)Qr, b_ = *(const u16x8*)(Qr + 8);
            #pragma unroll
            for (int j = 0; j < 8; ++j) { qreg[j] = bf16_to_f32(a[j]); qreg[8 + j] = bf16_to_f32(b_[j]); }
        }
        float p[32]; float mmax = -1e30f;
        #pragma unroll
        for (int k = 0; k < 32; ++k) {
            const unsigned short* Kr = &qkvb[4096 + k * 128 + hd * 16];
            u16x8 a = *(const u16x8*)Kr, b_ = *(const u16x8*)(Kr + 8);
            float s_ = 0.f;
            #pragma unroll
            for (int j = 0; j < 8; ++j)
                s_ += qreg[j] * bf16_to_f32(a[j]) + qreg[8 + j] * bf16_to_f32(b_[j]);
            s_ *= 0.25f;
            p[k] = s_;
            if (k <= q) mmax = fmaxf(mmax, s_);
        }
        float den = 0.f;
        #pragma unroll
        for (int k = 0; k < 32; ++k) {
            float e = (k <= q) ? __expf(p[k] - mmax) : 0.f;
            p[k] = e; den += e;
        }
        float rd = 1.f / den;
        float ctx[16];
        #pragma unroll
        for (int j = 0; j < 16; ++j) ctx[j] = 0.f;
        #pragma unroll
        for (int k = 0; k < 32; ++k) {
            const unsigned short* Vr = &qkvb[2 * 4096 + k * 128 + hd * 16];
            u16x8 a = *(const u16x8*)Vr, b_ = *(const u16x8*)(Vr + 8);
            float pk_ = p[k];
            #pragma unroll
            for (int j = 0; j < 8; ++j) { ctx[j] += pk_ * bf16_to_f32(a[j]); ctx[8 + j] += pk_ * bf16_to_f32(b_[j]); }
        }
        u16x8 o0, o1;
        #pragma unroll
        for (int j = 0; j < 8; ++j) { o0[j] = f32_to_bf16(ctx[j] * rd); o1[j] = f32_to_bf16(ctx[8 + j] * rd); }
        int byte0 = (q * 256 + (hd * 16) * 2) ^ ((q & 7) << 4);
        int byte1 = (q * 256 + (hd * 16 + 8) * 2) ^ ((q & 7) << 4);
        *(u16x8*)((char*)ctxb + byte0) = o0;
        *(u16x8*)((char*)ctxb + byte1) = o1;
    }
    __syncthreads();

    // ---- P4: X1 = ctx @ Wo + bo + X  (16 n-tiles, K=128) ----
    {
        const unsigned short* ctxb = hb;
        u16x8 afr[2][4];
        #pragma unroll
        for (int m = 0; m < 2; ++m)
            #pragma unroll
            for (int kk = 0; kk < 4; ++kk)
                afr[m][kk] = ldsA(ctxb, m * 16 + (lane & 15), kk * 32 + (lane >> 4) * 8, 256);
        #pragma unroll
        for (int ni = 0; ni < 4; ++ni) {
            int nt = wv * 4 + ni;
            u16x8 bfr[4];
            #pragma unroll
            for (int kk = 0; kk < 4; ++kk) bfr[kk] = ldgB(WTo, 128, nt, kk, lane);
            f32x4 acc0 = Z, acc1 = Z;
            #pragma unroll
            for (int kk = 0; kk < 4; ++kk) {
                acc0 = mfma16(afr[0][kk], bfr[kk], acc0);
                acc1 = mfma16(afr[1][kk], bfr[kk], acc1);
            }
            int col = nt * 16 + (lane & 15);
            float bocol = bo[col];
            #pragma unroll
            for (int reg = 0; reg < 4; ++reg) {
                int r0 = (lane >> 4) * 4 + reg;
                xs[r0][col]      += acc0[reg] + bocol;   // residual 1, in place
                xs[16 + r0][col] += acc1[reg] + bocol;
            }
        }
    }
    __syncthreads();
    // ---- P5: LN2 ----
    ln_bf16(xs, hb, ln_g, ln_b, tid);
    __syncthreads();

    // ---- P6: FFN in 4 chunks of 256 FF cols; acc2 persists in AGPRs ----
    {
        unsigned short* fch = qkvb;                      // overlay: QKV dead
        f32x4 acc2[2][4];
        #pragma unroll
        for (int m = 0; m < 2; ++m)
            #pragma unroll
            for (int ni = 0; ni < 4; ++ni) acc2[m][ni] = Z;

        for (int c = 0; c < 4; ++c) {
            // FFN1 chunk -> relu -> fch (swz bf16 [32][256])
            u16x8 afr1[2][8];
            #pragma unroll
            for (int m = 0; m < 2; ++m)
                #pragma unroll
                for (int kk = 0; kk < 8; ++kk)
                    afr1[m][kk] = ldsA(hb, m * 16 + (lane & 15), kk * 32 + (lane >> 4) * 8, 512);
            #pragma unroll
            for (int ni = 0; ni < 4; ++ni) {
                int fn = c * 16 + wv * 4 + ni;           // global FF n-tile
                u16x8 bfr[8];
                #pragma unroll
                for (int kk = 0; kk < 8; ++kk) bfr[kk] = ldgB(WT1, 256, fn, kk, lane);
                f32x4 f0 = Z, f1 = Z;
                #pragma unroll
                for (int kk = 0; kk < 8; ++kk) {
                    f0 = mfma16(afr1[0][kk], bfr[kk], f0);
                    f1 = mfma16(afr1[1][kk], bfr[kk], f1);
                }
                float b1c = b1[fn * 16 + (lane & 15)];
                int colc = (wv * 4 + ni) * 16 + (lane & 15);
                #pragma unroll
                for (int reg = 0; reg < 4; ++reg) {
                    int r0 = (lane >> 4) * 4 + reg;
                    {
                        int byte = (r0 * 512 + colc * 2) ^ ((r0 & 7) << 4);
                        *(unsigned short*)((char*)fch + byte) = f32_to_bf16(fmaxf(f0[reg] + b1c, 0.f));
                    }
                    {
                        int r1 = 16 + r0;
                        int byte = (r1 * 512 + colc * 2) ^ ((r1 & 7) << 4);
                        *(unsigned short*)((char*)fch + byte) = f32_to_bf16(fmaxf(f1[reg] + b1c, 0.f));
                    }
                }
            }
            __syncthreads();
            // FFN2 partial: acc2 += fch @ WT2[:, c*256 +: 256]
            u16x8 afr2[2][8];
            #pragma unroll
            for (int m = 0; m < 2; ++m)
                #pragma unroll
                for (int kk = 0; kk < 8; ++kk)
                    afr2[m][kk] = ldsA(fch, m * 16 + (lane & 15), kk * 32 + (lane >> 4) * 8, 512);
            #pragma unroll
            for (int ni = 0; ni < 4; ++ni) {
                int nt = wv * 4 + ni;
                u16x8 bfr[8];
                #pragma unroll
                for (int kk = 0; kk < 8; ++kk) bfr[kk] = ldgB(WT2 + c * 256, 1024, nt, kk, lane);
                #pragma unroll
                for (int kk = 0; kk < 8; ++kk) {
                    acc2[0][ni] = mfma16(afr2[0][kk], bfr[kk], acc2[0][ni]);
                    acc2[1][ni] = mfma16(afr2[1][kk], bfr[kk], acc2[1][ni]);
                }
            }
            __syncthreads();
        }
        // epilogue: + b2 + X1 -> out
        float* outb = out + (size_t)b * (TT * EMB);
        #pragma unroll
        for (int ni = 0; ni < 4; ++ni) {
            int col = (wv * 4 + ni) * 16 + (lane & 15);
            float b2c = b2[col];
            #pragma unroll
            for (int reg = 0; reg < 4; ++reg) {
                int r0 = (lane >> 4) * 4 + reg;
                outb[r0 * EMB + col]        = acc2[0][ni][reg] + b2c + xs[r0][col];
                outb[(16 + r0) * EMB + col] = acc2[1][ni][reg] + b2c + xs[16 + r0][col];
            }
        }
    }
}

extern "C" void kernel_launch(void* const* d_in, const int* in_sizes, int n_in,
                              void* d_out, int out_size, void* d_ws, size_t ws_size,
                              hipStream_t stream) {
    const float* X    = (const float*)d_in[0];
    const float* ln_g = (const float*)d_in[1];
    const float* ln_b = (const float*)d_in[2];
    const float* Wq   = (const float*)d_in[3];
    const float* bq   = (const float*)d_in[4];
    const float* Wk   = (const float*)d_in[5];
    const float* bk   = (const float*)d_in[6];
    const float* Wv   = (const float*)d_in[7];
    const float* bv   = (const float*)d_in[8];
    const float* Wo   = (const float*)d_in[9];
    const float* bo   = (const float*)d_in[10];
    const float* W1   = (const float*)d_in[11];
    const float* b1   = (const float*)d_in[12];
    const float* W2   = (const float*)d_in[13];
    const float* b2   = (const float*)d_in[14];
    unsigned short* ws = (unsigned short*)d_ws;
    float* O = (float*)d_out;

    wconv<<<2560, 256, 0, stream>>>(Wq, Wk, Wv, Wo, W1, W2, ws);
    attn_block_mfma<<<4096, 256, 0, stream>>>(X, ln_g, ln_b, bq, bk, bv, bo, b1, b2, ws, O);
}

// Round 3
// 785.340 us; speedup vs baseline: 8.8996x; 1.0956x over previous
//
#include <hip/hip_runtime.h>
#include <math.h>

typedef __attribute__((ext_vector_type(8))) __bf16 bf16x8;
typedef __attribute__((ext_vector_type(8))) unsigned short u16x8;
typedef __attribute__((ext_vector_type(4))) unsigned short u16x4;
typedef __attribute__((ext_vector_type(4))) float f32x4;

namespace {
constexpr int TT  = 32;
constexpr int EMB = 256;
constexpr int HD  = 128;
constexpr int FF  = 1024;
constexpr float EPSV = 1e-5f;

// fragment-ordered weight regions in ws (ushort elements).
// frag = (nt*KK + kk); elem = (frag*64 + lane)*8 + j  holds
// W^T[nt*16 + (lane&15)][kk*32 + (lane>>4)*8 + j]
constexpr int WS_QKV = 0;        // 24 nt x 8 kk x 512
constexpr int WS_O   = 98304;    // 16 nt x 4 kk x 512
constexpr int WS_1   = 131072;   // 64 nt x 8 kk x 512
constexpr int WS_2   = 393216;   // 16 nt x 32 kk x 512

__device__ __forceinline__ unsigned short f32_to_bf16(float f) {
    unsigned int u = __builtin_bit_cast(unsigned int, f);
    u += 0x7FFFu + ((u >> 16) & 1u);           // RNE; inputs finite
    return (unsigned short)(u >> 16);
}
__device__ __forceinline__ float bf16_to_f32(unsigned short h) {
    return __builtin_bit_cast(float, ((unsigned int)h) << 16);
}
__device__ __forceinline__ f32x4 mfma16(u16x8 a, u16x8 b, f32x4 c) {
    return __builtin_amdgcn_mfma_f32_16x16x32_bf16(
        __builtin_bit_cast(bf16x8, a), __builtin_bit_cast(bf16x8, b), c, 0, 0, 0);
}
// byte-XOR swizzle for bf16 LDS tiles: spreads row-starts over all 32 banks, 2-way max
__device__ __forceinline__ int swzB(int row) { return ((row & 7) << 4) | ((row & 8) << 2); }
// dword-index swizzle for the fp32 xs tile (16B-safe: xor is multiple of 4 dwords)
__device__ __forceinline__ int xidx(int r, int c) { return (r * 256 + c) ^ ((r & 7) << 2); }

__device__ __forceinline__ u16x8 ldsA(const unsigned short* base, int row, int k0, int rowBytes) {
    int byte = (row * rowBytes + k0 * 2) ^ swzB(row);
    return *(const u16x8*)((const char*)base + byte);
}
__device__ __forceinline__ u16x8 ldgF(const unsigned short* base, int frag, int lane) {
    return *(const u16x8*)(base + ((size_t)frag * 64 + lane) * 8);   // 1KB/wave, coalesced
}

// LN of swizzled fp32 xs -> swizzled bf16 tile (rowBytes=512).
// 8 threads/row, interleaved float4 columns (bank-packed reads).
__device__ __forceinline__ void ln_bf16(const float* xsf, unsigned short* outb,
                                        const float* __restrict__ g, const float* __restrict__ bb,
                                        int tid) {
    const int r = tid >> 3, sub = tid & 7;
    float4 vv[8];
    float s = 0.f, ss = 0.f;
    #pragma unroll
    for (int j = 0; j < 8; ++j) {
        int c = sub * 4 + j * 32;
        float4 v = *(const float4*)&xsf[xidx(r, c)];
        vv[j] = v;
        s  += (v.x + v.y) + (v.z + v.w);
        ss += (v.x * v.x + v.y * v.y) + (v.z * v.z + v.w * v.w);
    }
    #pragma unroll
    for (int w = 1; w < 8; w <<= 1) { s += __shfl_xor(s, w, 64); ss += __shfl_xor(ss, w, 64); }
    float mu  = s * (1.f / EMB);
    float inv = rsqrtf(fmaxf(ss * (1.f / EMB) - mu * mu, 0.f) + EPSV);
    #pragma unroll
    for (int j = 0; j < 8; ++j) {
        int c = sub * 4 + j * 32;
        float4 v = vv[j];
        float4 g4 = *(const float4*)&g[c];
        float4 b4 = *(const float4*)&bb[c];
        u16x4 pk;
        pk[0] = f32_to_bf16((v.x - mu) * inv * g4.x + b4.x);
        pk[1] = f32_to_bf16((v.y - mu) * inv * g4.y + b4.y);
        pk[2] = f32_to_bf16((v.z - mu) * inv * g4.z + b4.z);
        pk[3] = f32_to_bf16((v.w - mu) * inv * g4.w + b4.w);
        int byte = (r * 512 + c * 2) ^ swzB(r);
        *(u16x4*)((char*)outb + byte) = pk;
    }
}
} // namespace

// one-shot weight convert: fp32 -> bf16 fragment-ordered layout in ws
__global__ __launch_bounds__(256) void wconv(
    const float* __restrict__ Wq, const float* __restrict__ Wk, const float* __restrict__ Wv,
    const float* __restrict__ Wo, const float* __restrict__ W1, const float* __restrict__ W2,
    unsigned short* __restrict__ ws) {
    int e = blockIdx.x * 256 + threadIdx.x;     // 0..655359
    int j, lane, kk, nt, n, k;
    float v;
    if (e < WS_O) {                             // QKV, K=256, 24 nt
        int t = e; j = t & 7; lane = (t >> 3) & 63; int r2 = t >> 9;
        kk = r2 & 7; nt = r2 >> 3;
        n = nt * 16 + (lane & 15); k = kk * 32 + (lane >> 4) * 8 + j;
        const float* W = (n < 128) ? Wq : ((n < 256) ? Wk : Wv);
        v = W[k * HD + (n & 127)];
    } else if (e < WS_1) {                      // Wo, K=128, 16 nt
        int t = e - WS_O; j = t & 7; lane = (t >> 3) & 63; int r2 = t >> 9;
        kk = r2 & 3; nt = r2 >> 2;
        n = nt * 16 + (lane & 15); k = kk * 32 + (lane >> 4) * 8 + j;
        v = Wo[k * EMB + n];
    } else if (e < WS_2) {                      // W1, K=256, 64 nt
        int t = e - WS_1; j = t & 7; lane = (t >> 3) & 63; int r2 = t >> 9;
        kk = r2 & 7; nt = r2 >> 3;
        n = nt * 16 + (lane & 15); k = kk * 32 + (lane >> 4) * 8 + j;
        v = W1[k * FF + n];
    } else {                                    // W2, K=1024, 16 nt
        int t = e - WS_2; j = t & 7; lane = (t >> 3) & 63; int r2 = t >> 9;
        kk = r2 & 31; nt = r2 >> 5;
        n = nt * 16 + (lane & 15); k = kk * 32 + (lane >> 4) * 8 + j;
        v = W2[k * EMB + n];
    }
    ws[e] = f32_to_bf16(v);
}

// one block per sequence; 4 waves; LDS 72KB -> 2 blocks/CU; VGPR budget 256 (2 waves/EU)
__global__ __attribute__((amdgpu_flat_work_group_size(256, 256), amdgpu_waves_per_eu(2, 2)))
void attn_block_mfma(
    const float* __restrict__ X, const float* __restrict__ ln_g, const float* __restrict__ ln_b,
    const float* __restrict__ bq, const float* __restrict__ bk, const float* __restrict__ bv,
    const float* __restrict__ bo, const float* __restrict__ b1, const float* __restrict__ b2,
    const unsigned short* __restrict__ ws, float* __restrict__ out) {
    __shared__ float xsf[TT * EMB];             // 32KB: X, then X1 (swz dwords)
    __shared__ unsigned short hb[TT * EMB];     // 16KB: h then h2 (swz, rb=512)
    __shared__ unsigned short qkvb[3 * TT * HD];// 24KB: Q|K|V (swz, rb=256); Q->ctx; K,V -> FFN chunk

    const unsigned short* WTqkv = ws + WS_QKV;
    const unsigned short* WTo   = ws + WS_O;
    const unsigned short* WT1   = ws + WS_1;
    const unsigned short* WT2   = ws + WS_2;

    const int tid  = threadIdx.x;
    const int wv   = tid >> 6;
    const int lane = tid & 63;
    const int b    = blockIdx.x;
    const f32x4 Z  = {0.f, 0.f, 0.f, 0.f};
    const float* Xb = X + (size_t)b * (TT * EMB);

    // ---- P0: load X tile (swizzled store) ----
    {
        const float4* src = (const float4*)Xb;
        #pragma unroll
        for (int i = 0; i < 8; ++i) {
            int f = tid + 256 * i;
            int r = f >> 6, c = (f & 63) * 4;
            *(float4*)&xsf[xidx(r, c)] = src[f];
        }
    }
    __syncthreads();
    // ---- P1: LN1 ----
    ln_bf16(xsf, hb, ln_g, ln_b, tid);
    __syncthreads();

    // ---- P2: QKV = h @ Wqkv + b  (nt = wv + 4i, i<6; 2-deep B pipeline) ----
    {
        u16x8 bfr[2][8];
        #pragma unroll
        for (int kk = 0; kk < 8; ++kk) bfr[0][kk] = ldgF(WTqkv, wv * 8 + kk, lane);
        u16x8 afr[2][8];
        #pragma unroll
        for (int m = 0; m < 2; ++m)
            #pragma unroll
            for (int kk = 0; kk < 8; ++kk)
                afr[m][kk] = ldsA(hb, m * 16 + (lane & 15), kk * 32 + (lane >> 4) * 8, 512);
        #pragma unroll
        for (int i = 0; i < 6; ++i) {
            int nt = wv + i * 4;
            if (i < 5) {
                #pragma unroll
                for (int kk = 0; kk < 8; ++kk)
                    bfr[(i & 1) ^ 1][kk] = ldgF(WTqkv, (nt + 4) * 8 + kk, lane);
            }
            f32x4 a0 = Z, a1 = Z;
            #pragma unroll
            for (int kk = 0; kk < 8; ++kk) {
                a0 = mfma16(afr[0][kk], bfr[i & 1][kk], a0);
                a1 = mfma16(afr[1][kk], bfr[i & 1][kk], a1);
            }
            int gcol = nt * 16 + (lane & 15);
            int mat = gcol >> 7, c = gcol & 127;
            const float* bias = (mat == 0) ? bq : ((mat == 1) ? bk : bv);
            float bcol = bias[c];
            #pragma unroll
            for (int reg = 0; reg < 4; ++reg) {
                int r0 = (lane >> 4) * 4 + reg;
                int by0 = mat * 8192 + ((r0 * 256 + c * 2) ^ swzB(r0));
                int by1 = mat * 8192 + (((16 + r0) * 256 + c * 2) ^ swzB(16 + r0));
                *(unsigned short*)((char*)qkvb + by0) = f32_to_bf16(a0[reg] + bcol);
                *(unsigned short*)((char*)qkvb + by1) = f32_to_bf16(a1[reg] + bcol);
            }
        }
    }
    __syncthreads();

    // ---- P3: attention (VALU). thread=(head,q). ctx overwrites own Q slots ----
    {
        const int hd = tid >> 5, q = tid & 31;
        float qreg[16];
        {
            int by0 = (q * 256 + hd * 32) ^ swzB(q);
            int by1 = (q * 256 + hd * 32 + 16) ^ swzB(q);
            u16x8 a = *(const u16x8*)((const char*)qkvb + by0);
            u16x8 b_ = *(const u16x8*)((const char*)qkvb + by1);
            #pragma unroll
            for (int j = 0; j < 8; ++j) { qreg[j] = bf16_to_f32(a[j]); qreg[8 + j] = bf16_to_f32(b_[j]); }
        }
        float p[32]; float mmax = -1e30f;
        #pragma unroll
        for (int k = 0; k < 32; ++k) {
            int by0 = 8192 + ((k * 256 + hd * 32) ^ swzB(k));
            int by1 = 8192 + ((k * 256 + hd * 32 + 16) ^ swzB(k));
            u16x8 a = *(const u16x8*)((const char*)qkvb + by0);
            u16x8 b_ = *(const u16x8*)((const char*)qkvb + by1);
            float s_ = 0.f;
            #pragma unroll
            for (int j = 0; j < 8; ++j)
                s_ += qreg[j] * bf16_to_f32(a[j]) + qreg[8 + j] * bf16_to_f32(b_[j]);
            s_ *= 0.25f;
            p[k] = s_;
            if (k <= q) mmax = fmaxf(mmax, s_);
        }
        float den = 0.f;
        #pragma unroll
        for (int k = 0; k < 32; ++k) {
            float e = (k <= q) ? __expf(p[k] - mmax) : 0.f;
            p[k] = e; den += e;
        }
        float rd = 1.f / den;
        float ctx[16];
        #pragma unroll
        for (int j = 0; j < 16; ++j) ctx[j] = 0.f;
        #pragma unroll
        for (int k = 0; k < 32; ++k) {
            int by0 = 16384 + ((k * 256 + hd * 32) ^ swzB(k));
            int by1 = 16384 + ((k * 256 + hd * 32 + 16) ^ swzB(k));
            u16x8 a = *(const u16x8*)((const char*)qkvb + by0);
            u16x8 b_ = *(const u16x8*)((const char*)qkvb + by1);
            float pk_ = p[k];
            #pragma unroll
            for (int j = 0; j < 8; ++j) { ctx[j] += pk_ * bf16_to_f32(a[j]); ctx[8 + j] += pk_ * bf16_to_f32(b_[j]); }
        }
        u16x8 o0, o1;
        #pragma unroll
        for (int j = 0; j < 8; ++j) { o0[j] = f32_to_bf16(ctx[j] * rd); o1[j] = f32_to_bf16(ctx[8 + j] * rd); }
        int by0 = (q * 256 + hd * 32) ^ swzB(q);
        int by1 = (q * 256 + hd * 32 + 16) ^ swzB(q);
        *(u16x8*)((char*)qkvb + by0) = o0;
        *(u16x8*)((char*)qkvb + by1) = o1;
    }
    __syncthreads();

    // ---- P4: X1 = ctx @ Wo + bo + X  (16 nt; K=128; 2-deep) ----
    {
        u16x8 bfr[2][4];
        #pragma unroll
        for (int kk = 0; kk < 4; ++kk) bfr[0][kk] = ldgF(WTo, (wv * 4) * 4 + kk, lane);
        u16x8 afr[2][4];
        #pragma unroll
        for (int m = 0; m < 2; ++m)
            #pragma unroll
            for (int kk = 0; kk < 4; ++kk)
                afr[m][kk] = ldsA(qkvb, m * 16 + (lane & 15), kk * 32 + (lane >> 4) * 8, 256);
        #pragma unroll
        for (int ni = 0; ni < 4; ++ni) {
            int nt = wv * 4 + ni;
            if (ni < 3) {
                #pragma unroll
                for (int kk = 0; kk < 4; ++kk)
                    bfr[(ni & 1) ^ 1][kk] = ldgF(WTo, (nt + 1) * 4 + kk, lane);
            }
            f32x4 a0 = Z, a1 = Z;
            #pragma unroll
            for (int kk = 0; kk < 4; ++kk) {
                a0 = mfma16(afr[0][kk], bfr[ni & 1][kk], a0);
                a1 = mfma16(afr[1][kk], bfr[ni & 1][kk], a1);
            }
            int col = nt * 16 + (lane & 15);
            float bocol = bo[col];
            #pragma unroll
            for (int reg = 0; reg < 4; ++reg) {
                int r0 = (lane >> 4) * 4 + reg;
                xsf[xidx(r0, col)]      += a0[reg] + bocol;   // residual 1
                xsf[xidx(16 + r0, col)] += a1[reg] + bocol;
            }
        }
    }
    __syncthreads();
    // ---- P5: LN2 ----
    ln_bf16(xsf, hb, ln_g, ln_b, tid);
    __syncthreads();

    // ---- P6: FFN, 4 chunks of 256 FF cols; fch overlays K|V region ----
    {
        unsigned short* fch = qkvb + 4096;       // 16KB, rb=512, swz
        f32x4 acc2[2][4];
        #pragma unroll
        for (int m = 0; m < 2; ++m)
            #pragma unroll
            for (int ni = 0; ni < 4; ++ni) acc2[m][ni] = Z;

        #pragma unroll 1
        for (int ch = 0; ch < 4; ++ch) {
            // FFN1: relu(h2 @ W1 chunk + b1) -> fch
            u16x8 b1f[2][8];
            {
                int fn = ch * 16 + wv * 4;
                #pragma unroll
                for (int kk = 0; kk < 8; ++kk) b1f[0][kk] = ldgF(WT1, fn * 8 + kk, lane);
            }
            u16x8 afr1[2][8];
            #pragma unroll
            for (int m = 0; m < 2; ++m)
                #pragma unroll
                for (int kk = 0; kk < 8; ++kk)
                    afr1[m][kk] = ldsA(hb, m * 16 + (lane & 15), kk * 32 + (lane >> 4) * 8, 512);
            #pragma unroll
            for (int ni = 0; ni < 4; ++ni) {
                int fn = ch * 16 + wv * 4 + ni;
                if (ni < 3) {
                    #pragma unroll
                    for (int kk = 0; kk < 8; ++kk)
                        b1f[(ni & 1) ^ 1][kk] = ldgF(WT1, (fn + 1) * 8 + kk, lane);
                }
                f32x4 f0 = Z, f1 = Z;
                #pragma unroll
                for (int kk = 0; kk < 8; ++kk) {
                    f0 = mfma16(afr1[0][kk], b1f[ni & 1][kk], f0);
                    f1 = mfma16(afr1[1][kk], b1f[ni & 1][kk], f1);
                }
                float b1c = b1[fn * 16 + (lane & 15)];
                int colc = (wv * 4 + ni) * 16 + (lane & 15);
                #pragma unroll
                for (int reg = 0; reg < 4; ++reg) {
                    int r0 = (lane >> 4) * 4 + reg;
                    int byA = (r0 * 512 + colc * 2) ^ swzB(r0);
                    int byB = ((16 + r0) * 512 + colc * 2) ^ swzB(16 + r0);
                    *(unsigned short*)((char*)fch + byA) = f32_to_bf16(fmaxf(f0[reg] + b1c, 0.f));
                    *(unsigned short*)((char*)fch + byB) = f32_to_bf16(fmaxf(f1[reg] + b1c, 0.f));
                }
            }
            __syncthreads();
            // FFN2: acc2 += fch @ W2[ch-slice]
            u16x8 b2f[2][8];
            #pragma unroll
            for (int kk = 0; kk < 8; ++kk)
                b2f[0][kk] = ldgF(WT2, (wv * 4) * 32 + ch * 8 + kk, lane);
            u16x8 afr2[2][8];
            #pragma unroll
            for (int m = 0; m < 2; ++m)
                #pragma unroll
                for (int kk = 0; kk < 8; ++kk)
                    afr2[m][kk] = ldsA(fch, m * 16 + (lane & 15), kk * 32 + (lane >> 4) * 8, 512);
            #pragma unroll
            for (int ni = 0; ni < 4; ++ni) {
                int nt = wv * 4 + ni;
                if (ni < 3) {
                    #pragma unroll
                    for (int kk = 0; kk < 8; ++kk)
                        b2f[(ni & 1) ^ 1][kk] = ldgF(WT2, (nt + 1) * 32 + ch * 8 + kk, lane);
                }
                #pragma unroll
                for (int kk = 0; kk < 8; ++kk) {
                    acc2[0][ni] = mfma16(afr2[0][kk], b2f[ni & 1][kk], acc2[0][ni]);
                    acc2[1][ni] = mfma16(afr2[1][kk], b2f[ni & 1][kk], acc2[1][ni]);
                }
            }
            __syncthreads();
        }
        // epilogue: + b2 + X1 -> out
        float* outb = out + (size_t)b * (TT * EMB);
        #pragma unroll
        for (int ni = 0; ni < 4; ++ni) {
            int col = (wv * 4 + ni) * 16 + (lane & 15);
            float b2c = b2[col];
            #pragma unroll
            for (int reg = 0; reg < 4; ++reg) {
                int r0 = (lane >> 4) * 4 + reg;
                outb[r0 * EMB + col]        = acc2[0][ni][reg] + b2c + xsf[xidx(r0, col)];
                outb[(16 + r0) * EMB + col] = acc2[1][ni][reg] + b2c + xsf[xidx(16 + r0, col)];
            }
        }
    }
}

extern "C" void kernel_launch(void* const* d_in, const int* in_sizes, int n_in,
                              void* d_out, int out_size, void* d_ws, size_t ws_size,
                              hipStream_t stream) {
    const float* X    = (const float*)d_in[0];
    const float* ln_g = (const float*)d_in[1];
    const float* ln_b = (const float*)d_in[2];
    const float* Wq   = (const float*)d_in[3];
    const float* bq   = (const float*)d_in[4];
    const float* Wk   = (const float*)d_in[5];
    const float* bk   = (const float*)d_in[6];
    const float* Wv   = (const float*)d_in[7];
    const float* bv   = (const float*)d_in[8];
    const float* Wo   = (const float*)d_in[9];
    const float* bo   = (const float*)d_in[10];
    const float* W1   = (const float*)d_in[11];
    const float* b1   = (const float*)d_in[12];
    const float* W2   = (const float*)d_in[13];
    const float* b2   = (const float*)d_in[14];
    unsigned short* ws = (unsigned short*)d_ws;
    float* O = (float*)d_out;

    wconv<<<2560, 256, 0, stream>>>(Wq, Wk, Wv, Wo, W1, W2, ws);
    attn_block_mfma<<<4096, 256, 0, stream>>>(X, ln_g, ln_b, bq, bk, bv, bo, b1, b2, ws, O);
}

// Round 4
// 612.742 us; speedup vs baseline: 11.4065x; 1.2817x over previous
//
#include <hip/hip_runtime.h>
#include <math.h>

typedef __attribute__((ext_vector_type(8))) __bf16 bf16x8;
typedef __attribute__((ext_vector_type(8))) unsigned short u16x8;
typedef __attribute__((ext_vector_type(4))) unsigned short u16x4;
typedef __attribute__((ext_vector_type(4))) float f32x4;

namespace {
constexpr int TT  = 32;
constexpr int EMB = 256;
constexpr int HD  = 128;
constexpr int FF  = 1024;
constexpr float EPSV = 1e-5f;

// fragment-ordered weight regions in ws (ushort elements).
// frag = (nt*KK + kk); elem = (frag*64 + lane)*8 + j  holds
// W^T[nt*16 + (lane&15)][kk*32 + (lane>>4)*8 + j]
constexpr int WS_QKV = 0;        // 24 nt x 8 kk x 512
constexpr int WS_O   = 98304;    // 16 nt x 4 kk x 512
constexpr int WS_1   = 131072;   // 64 nt x 8 kk x 512
constexpr int WS_2   = 393216;   // 16 nt x 32 kk x 512

__device__ __forceinline__ unsigned short f32_to_bf16(float f) {
    unsigned int u = __builtin_bit_cast(unsigned int, f);
    u += 0x7FFFu + ((u >> 16) & 1u);           // RNE; inputs finite
    return (unsigned short)(u >> 16);
}
__device__ __forceinline__ float bf16_to_f32(unsigned short h) {
    return __builtin_bit_cast(float, ((unsigned int)h) << 16);
}
__device__ __forceinline__ f32x4 mfma16(u16x8 a, u16x8 b, f32x4 c) {
    return __builtin_amdgcn_mfma_f32_16x16x32_bf16(
        __builtin_bit_cast(bf16x8, a), __builtin_bit_cast(bf16x8, b), c, 0, 0, 0);
}
// byte-XOR swizzle for bf16 LDS tiles: spreads row-starts over banks, ~2-way max
__device__ __forceinline__ int swzB(int row) { return ((row & 7) << 4) | ((row & 8) << 2); }
// dword-index swizzle for the fp32 xs tile (16B-safe)
__device__ __forceinline__ int xidx(int r, int c) { return (r * 256 + c) ^ ((r & 7) << 2); }

__device__ __forceinline__ u16x8 ldsA(const unsigned short* base, int row, int k0, int rowBytes) {
    int byte = (row * rowBytes + k0 * 2) ^ swzB(row);
    return *(const u16x8*)((const char*)base + byte);
}
__device__ __forceinline__ u16x8 ldgF(const unsigned short* base, int frag, int lane) {
    return *(const u16x8*)(base + ((size_t)frag * 64 + lane) * 8);   // 1KB/wave, coalesced
}

// LN of swizzled fp32 xs -> swizzled bf16 tile (rowBytes=512). 8 threads/row.
__device__ __forceinline__ void ln_bf16(const float* xsf, unsigned short* outb,
                                        const float* __restrict__ g, const float* __restrict__ bb,
                                        int tid) {
    const int r = tid >> 3, sub = tid & 7;
    float4 vv[8];
    float s = 0.f, ss = 0.f;
    #pragma unroll
    for (int j = 0; j < 8; ++j) {
        int c = sub * 4 + j * 32;
        float4 v = *(const float4*)&xsf[xidx(r, c)];
        vv[j] = v;
        s  += (v.x + v.y) + (v.z + v.w);
        ss += (v.x * v.x + v.y * v.y) + (v.z * v.z + v.w * v.w);
    }
    #pragma unroll
    for (int w = 1; w < 8; w <<= 1) { s += __shfl_xor(s, w, 64); ss += __shfl_xor(ss, w, 64); }
    float mu  = s * (1.f / EMB);
    float inv = rsqrtf(fmaxf(ss * (1.f / EMB) - mu * mu, 0.f) + EPSV);
    #pragma unroll
    for (int j = 0; j < 8; ++j) {
        int c = sub * 4 + j * 32;
        float4 v = vv[j];
        float4 g4 = *(const float4*)&g[c];
        float4 b4 = *(const float4*)&bb[c];
        u16x4 pk;
        pk[0] = f32_to_bf16((v.x - mu) * inv * g4.x + b4.x);
        pk[1] = f32_to_bf16((v.y - mu) * inv * g4.y + b4.y);
        pk[2] = f32_to_bf16((v.z - mu) * inv * g4.z + b4.z);
        pk[3] = f32_to_bf16((v.w - mu) * inv * g4.w + b4.w);
        int byte = (r * 512 + c * 2) ^ swzB(r);
        *(u16x4*)((char*)outb + byte) = pk;
    }
}
} // namespace

// one-shot weight convert: fp32 -> bf16 fragment-ordered layout in ws
__global__ __launch_bounds__(256) void wconv(
    const float* __restrict__ Wq, const float* __restrict__ Wk, const float* __restrict__ Wv,
    const float* __restrict__ Wo, const float* __restrict__ W1, const float* __restrict__ W2,
    unsigned short* __restrict__ ws) {
    int e = blockIdx.x * 256 + threadIdx.x;     // 0..655359
    int j, lane, kk, nt, n, k;
    float v;
    if (e < WS_O) {                             // QKV, K=256, 24 nt
        int t = e; j = t & 7; lane = (t >> 3) & 63; int r2 = t >> 9;
        kk = r2 & 7; nt = r2 >> 3;
        n = nt * 16 + (lane & 15); k = kk * 32 + (lane >> 4) * 8 + j;
        const float* W = (n < 128) ? Wq : ((n < 256) ? Wk : Wv);
        v = W[k * HD + (n & 127)];
    } else if (e < WS_1) {                      // Wo, K=128, 16 nt
        int t = e - WS_O; j = t & 7; lane = (t >> 3) & 63; int r2 = t >> 9;
        kk = r2 & 3; nt = r2 >> 2;
        n = nt * 16 + (lane & 15); k = kk * 32 + (lane >> 4) * 8 + j;
        v = Wo[k * EMB + n];
    } else if (e < WS_2) {                      // W1, K=256, 64 nt
        int t = e - WS_1; j = t & 7; lane = (t >> 3) & 63; int r2 = t >> 9;
        kk = r2 & 7; nt = r2 >> 3;
        n = nt * 16 + (lane & 15); k = kk * 32 + (lane >> 4) * 8 + j;
        v = W1[k * FF + n];
    } else {                                    // W2, K=1024, 16 nt
        int t = e - WS_2; j = t & 7; lane = (t >> 3) & 63; int r2 = t >> 9;
        kk = r2 & 31; nt = r2 >> 5;
        n = nt * 16 + (lane & 15); k = kk * 32 + (lane >> 4) * 8 + j;
        v = W2[k * EMB + n];
    }
    ws[e] = f32_to_bf16(v);
}

// one block/sequence; 4 waves, each owns (m-half, n-quarter) -> peak live regs ~150,
// no spills. LDS 72KB -> 2 blocks/CU -> 2 waves/EU, so VGPR cap 256 is free.
__global__ __launch_bounds__(256, 2) void attn_block_mfma(
    const float* __restrict__ X, const float* __restrict__ ln_g, const float* __restrict__ ln_b,
    const float* __restrict__ bq, const float* __restrict__ bk, const float* __restrict__ bv,
    const float* __restrict__ bo, const float* __restrict__ b1, const float* __restrict__ b2,
    const unsigned short* __restrict__ ws, float* __restrict__ out) {
    __shared__ float xsf[TT * EMB];             // 32KB: X, then X1 (swz dwords)
    __shared__ unsigned short hb[TT * EMB];     // 16KB: h then h2 (swz, rb=512)
    __shared__ unsigned short qkvb[3 * TT * HD];// 24KB: Q|K|V (swz, rb=256); Q->ctx; K,V -> FFN chunk

    const unsigned short* WTqkv = ws + WS_QKV;
    const unsigned short* WTo   = ws + WS_O;
    const unsigned short* WT1   = ws + WS_1;
    const unsigned short* WT2   = ws + WS_2;

    const int tid  = threadIdx.x;
    const int wv   = tid >> 6;
    const int mh   = wv & 1;                    // m-half: rows mh*16..mh*16+15
    const int nh   = wv >> 1;                   // n-half
    const int lane = tid & 63;
    const int b    = blockIdx.x;
    const f32x4 Z  = {0.f, 0.f, 0.f, 0.f};
    const float* Xb = X + (size_t)b * (TT * EMB);
    const int arow = mh * 16 + (lane & 15);     // A-fragment row
    const int ak0  = (lane >> 4) * 8;           // A-fragment k base
    const int crow = mh * 16 + (lane >> 4) * 4; // C base row (m89 map)

    // ---- P0: load X tile (swizzled store) ----
    {
        const float4* src = (const float4*)Xb;
        #pragma unroll
        for (int i = 0; i < 8; ++i) {
            int f = tid + 256 * i;
            int r = f >> 6, c = (f & 63) * 4;
            *(float4*)&xsf[xidx(r, c)] = src[f];
        }
    }
    __syncthreads();
    // ---- P1: LN1 ----
    ln_bf16(xsf, hb, ln_g, ln_b, tid);
    __syncthreads();

    // ---- P2: QKV = h @ Wqkv + b  (wave: 12 nt x 1 m-tile, K=256) ----
    {
        u16x8 afr[8];
        #pragma unroll
        for (int kk = 0; kk < 8; ++kk) afr[kk] = ldsA(hb, arow, kk * 32 + ak0, 512);
        #pragma unroll 2
        for (int i = 0; i < 12; ++i) {
            int nt = nh * 12 + i;
            u16x8 bfr[8];
            #pragma unroll
            for (int kk = 0; kk < 8; ++kk) bfr[kk] = ldgF(WTqkv, nt * 8 + kk, lane);
            f32x4 e = Z, o = Z;
            #pragma unroll
            for (int kk = 0; kk < 8; kk += 2) {
                e = mfma16(afr[kk], bfr[kk], e);
                o = mfma16(afr[kk + 1], bfr[kk + 1], o);
            }
            f32x4 a = e + o;
            int gcol = nt * 16 + (lane & 15);
            int mat = gcol >> 7, c = gcol & 127;
            const float* bias = (mat == 0) ? bq : ((mat == 1) ? bk : bv);
            float bcol = bias[c];
            #pragma unroll
            for (int reg = 0; reg < 4; ++reg) {
                int r0 = crow + reg;
                int by = mat * 8192 + ((r0 * 256 + c * 2) ^ swzB(r0));
                *(unsigned short*)((char*)qkvb + by) = f32_to_bf16(a[reg] + bcol);
            }
        }
    }
    __syncthreads();

    // ---- P3: attention (VALU). thread=(head,q). ctx overwrites own Q slots ----
    {
        const int hd = tid >> 5, q = tid & 31;
        float qreg[16];
        {
            int by0 = (q * 256 + hd * 32) ^ swzB(q);
            int by1 = (q * 256 + hd * 32 + 16) ^ swzB(q);
            u16x8 a = *(const u16x8*)((const char*)qkvb + by0);
            u16x8 b_ = *(const u16x8*)((const char*)qkvb + by1);
            #pragma unroll
            for (int j = 0; j < 8; ++j) { qreg[j] = bf16_to_f32(a[j]); qreg[8 + j] = bf16_to_f32(b_[j]); }
        }
        float p[32]; float mmax = -1e30f;
        #pragma unroll
        for (int k = 0; k < 32; ++k) {
            int by0 = 8192 + ((k * 256 + hd * 32) ^ swzB(k));
            int by1 = 8192 + ((k * 256 + hd * 32 + 16) ^ swzB(k));
            u16x8 a = *(const u16x8*)((const char*)qkvb + by0);
            u16x8 b_ = *(const u16x8*)((const char*)qkvb + by1);
            float s_ = 0.f;
            #pragma unroll
            for (int j = 0; j < 8; ++j)
                s_ += qreg[j] * bf16_to_f32(a[j]) + qreg[8 + j] * bf16_to_f32(b_[j]);
            s_ *= 0.25f;
            p[k] = s_;
            if (k <= q) mmax = fmaxf(mmax, s_);
        }
        float den = 0.f;
        #pragma unroll
        for (int k = 0; k < 32; ++k) {
            float e = (k <= q) ? __expf(p[k] - mmax) : 0.f;
            p[k] = e; den += e;
        }
        float rd = 1.f / den;
        float ctx[16];
        #pragma unroll
        for (int j = 0; j < 16; ++j) ctx[j] = 0.f;
        #pragma unroll
        for (int k = 0; k < 32; ++k) {
            int by0 = 16384 + ((k * 256 + hd * 32) ^ swzB(k));
            int by1 = 16384 + ((k * 256 + hd * 32 + 16) ^ swzB(k));
            u16x8 a = *(const u16x8*)((const char*)qkvb + by0);
            u16x8 b_ = *(const u16x8*)((const char*)qkvb + by1);
            float pk_ = p[k];
            #pragma unroll
            for (int j = 0; j < 8; ++j) { ctx[j] += pk_ * bf16_to_f32(a[j]); ctx[8 + j] += pk_ * bf16_to_f32(b_[j]); }
        }
        u16x8 o0, o1;
        #pragma unroll
        for (int j = 0; j < 8; ++j) { o0[j] = f32_to_bf16(ctx[j] * rd); o1[j] = f32_to_bf16(ctx[8 + j] * rd); }
        int by0 = (q * 256 + hd * 32) ^ swzB(q);
        int by1 = (q * 256 + hd * 32 + 16) ^ swzB(q);
        *(u16x8*)((char*)qkvb + by0) = o0;
        *(u16x8*)((char*)qkvb + by1) = o1;
    }
    __syncthreads();

    // ---- P4: X1 = ctx @ Wo + bo + X  (wave: 8 nt x 1 m-tile, K=128) ----
    {
        u16x8 afr[4];
        #pragma unroll
        for (int kk = 0; kk < 4; ++kk) afr[kk] = ldsA(qkvb, arow, kk * 32 + ak0, 256);
        #pragma unroll 2
        for (int i = 0; i < 8; ++i) {
            int nt = nh * 8 + i;
            u16x8 bfr[4];
            #pragma unroll
            for (int kk = 0; kk < 4; ++kk) bfr[kk] = ldgF(WTo, nt * 4 + kk, lane);
            f32x4 e = Z, o = Z;
            e = mfma16(afr[0], bfr[0], e);
            o = mfma16(afr[1], bfr[1], o);
            e = mfma16(afr[2], bfr[2], e);
            o = mfma16(afr[3], bfr[3], o);
            f32x4 a = e + o;
            int col = nt * 16 + (lane & 15);
            float bocol = bo[col];
            #pragma unroll
            for (int reg = 0; reg < 4; ++reg) {
                int r0 = crow + reg;
                xsf[xidx(r0, col)] += a[reg] + bocol;   // residual 1
            }
        }
    }
    __syncthreads();
    // ---- P5: LN2 ----
    ln_bf16(xsf, hb, ln_g, ln_b, tid);
    __syncthreads();

    // ---- P6: FFN, 4 chunks of 256 FF cols; fch overlays K|V region ----
    {
        unsigned short* fch = qkvb + 4096;       // 16KB, rb=512, swz
        f32x4 acc2[8];                           // persistent FFN2 accumulators (static idx)
        #pragma unroll
        for (int i = 0; i < 8; ++i) acc2[i] = Z;

        #pragma unroll 1
        for (int ch = 0; ch < 4; ++ch) {
            // FFN1: relu(h2 @ W1 chunk + b1) -> fch
            u16x8 afr1[8];
            #pragma unroll
            for (int kk = 0; kk < 8; ++kk) afr1[kk] = ldsA(hb, arow, kk * 32 + ak0, 512);
            #pragma unroll 2
            for (int i = 0; i < 8; ++i) {
                int fn = ch * 16 + nh * 8 + i;
                u16x8 bfr[8];
                #pragma unroll
                for (int kk = 0; kk < 8; ++kk) bfr[kk] = ldgF(WT1, fn * 8 + kk, lane);
                f32x4 e = Z, o = Z;
                #pragma unroll
                for (int kk = 0; kk < 8; kk += 2) {
                    e = mfma16(afr1[kk], bfr[kk], e);
                    o = mfma16(afr1[kk + 1], bfr[kk + 1], o);
                }
                f32x4 f = e + o;
                float b1c = b1[fn * 16 + (lane & 15)];
                int colc = (nh * 8 + i) * 16 + (lane & 15);
                #pragma unroll
                for (int reg = 0; reg < 4; ++reg) {
                    int r0 = crow + reg;
                    int by = (r0 * 512 + colc * 2) ^ swzB(r0);
                    *(unsigned short*)((char*)fch + by) = f32_to_bf16(fmaxf(f[reg] + b1c, 0.f));
                }
            }
            __syncthreads();
            // FFN2: acc2 += fch @ W2[ch-slice]  (fully unrolled: static acc2 idx)
            u16x8 afr2[8];
            #pragma unroll
            for (int kk = 0; kk < 8; ++kk) afr2[kk] = ldsA(fch, arow, kk * 32 + ak0, 512);
            #pragma unroll
            for (int i = 0; i < 8; ++i) {
                int nt = nh * 8 + i;
                u16x8 bfr[8];
                #pragma unroll
                for (int kk = 0; kk < 8; ++kk) bfr[kk] = ldgF(WT2, nt * 32 + ch * 8 + kk, lane);
                f32x4 e = Z, o = Z;
                #pragma unroll
                for (int kk = 0; kk < 8; kk += 2) {
                    e = mfma16(afr2[kk], bfr[kk], e);
                    o = mfma16(afr2[kk + 1], bfr[kk + 1], o);
                }
                acc2[i] += e + o;
            }
            __syncthreads();
        }
        // epilogue: + b2 + X1 -> out
        float* outb = out + (size_t)b * (TT * EMB);
        #pragma unroll
        for (int i = 0; i < 8; ++i) {
            int col = (nh * 8 + i) * 16 + (lane & 15);
            float b2c = b2[col];
            #pragma unroll
            for (int reg = 0; reg < 4; ++reg) {
                int r0 = crow + reg;
                outb[r0 * EMB + col] = acc2[i][reg] + b2c + xsf[xidx(r0, col)];
            }
        }
    }
}

extern "C" void kernel_launch(void* const* d_in, const int* in_sizes, int n_in,
                              void* d_out, int out_size, void* d_ws, size_t ws_size,
                              hipStream_t stream) {
    const float* X    = (const float*)d_in[0];
    const float* ln_g = (const float*)d_in[1];
    const float* ln_b = (const float*)d_in[2];
    const float* Wq   = (const float*)d_in[3];
    const float* bq   = (const float*)d_in[4];
    const float* Wk   = (const float*)d_in[5];
    const float* bk   = (const float*)d_in[6];
    const float* Wv   = (const float*)d_in[7];
    const float* bv   = (const float*)d_in[8];
    const float* Wo   = (const float*)d_in[9];
    const float* bo   = (const float*)d_in[10];
    const float* W1   = (const float*)d_in[11];
    const float* b1   = (const float*)d_in[12];
    const float* W2   = (const float*)d_in[13];
    const float* b2   = (const float*)d_in[14];
    unsigned short* ws = (unsigned short*)d_ws;
    float* O = (float*)d_out;

    wconv<<<2560, 256, 0, stream>>>(Wq, Wk, Wv, Wo, W1, W2, ws);
    attn_block_mfma<<<4096, 256, 0, stream>>>(X, ln_g, ln_b, bq, bk, bv, bo, b1, b2, ws, O);
}

// Round 5
// 457.296 us; speedup vs baseline: 15.2838x; 1.3399x over previous
//
#include <hip/hip_runtime.h>
#include <math.h>

typedef __attribute__((ext_vector_type(8))) __bf16 bf16x8;
typedef __attribute__((ext_vector_type(8))) unsigned short u16x8;
typedef __attribute__((ext_vector_type(4))) unsigned short u16x4;
typedef __attribute__((ext_vector_type(4))) float f32x4;

namespace {
constexpr int EMB = 256;
constexpr int HD  = 128;
constexpr int FF  = 1024;
constexpr float EPSV = 1e-5f;
constexpr int M   = 128;      // rows per block = 4 sequences x 32

// fragment-ordered weight regions in ws (ushort elements).
// frag = (nt*KK + kk); elem = (frag*64 + lane)*8 + j  holds
// W^T[nt*16 + (lane&15)][kk*32 + (lane>>4)*8 + j]
constexpr int WS_QKV = 0;        // 24 nt x 8 kk x 512
constexpr int WS_O   = 98304;    // 16 nt x 4 kk x 512
constexpr int WS_1   = 131072;   // 64 nt x 8 kk x 512
constexpr int WS_2   = 393216;   // 16 nt x 32 kk x 512

__device__ __forceinline__ unsigned short f32_to_bf16(float f) {
    unsigned int u = __builtin_bit_cast(unsigned int, f);
    u += 0x7FFFu + ((u >> 16) & 1u);           // RNE; inputs finite
    return (unsigned short)(u >> 16);
}
__device__ __forceinline__ float bf16_to_f32(unsigned short h) {
    return __builtin_bit_cast(float, ((unsigned int)h) << 16);
}
__device__ __forceinline__ f32x4 mfma16(u16x8 a, u16x8 b, f32x4 c) {
    return __builtin_amdgcn_mfma_f32_16x16x32_bf16(
        __builtin_bit_cast(bf16x8, a), __builtin_bit_cast(bf16x8, b), c, 0, 0, 0);
}
// byte-XOR swizzle: spreads row-starts over banks (~2-way max), 16B-safe
__device__ __forceinline__ int swzB(int row) { return ((row & 7) << 4) | ((row & 8) << 2); }

__device__ __forceinline__ u16x8 ldsA256(const unsigned short* base, int row, int k0) {
    int byte = (row * 256 + k0 * 2) ^ swzB(row);
    return *(const u16x8*)((const char*)base + byte);
}
__device__ __forceinline__ u16x8 ldsA512(const unsigned short* base, int row, int k0) {
    int byte = (row * 512 + k0 * 2) ^ swzB(row);
    return *(const u16x8*)((const char*)base + byte);
}
__device__ __forceinline__ u16x8 ldgF(const unsigned short* base, int frag, int lane) {
    return *(const u16x8*)(base + ((size_t)frag * 64 + lane) * 8);   // 1KB/wave, coalesced
}
} // namespace

// one-shot weight convert: fp32 -> bf16 fragment-ordered layout in ws (unchanged)
__global__ __launch_bounds__(256) void wconv(
    const float* __restrict__ Wq, const float* __restrict__ Wk, const float* __restrict__ Wv,
    const float* __restrict__ Wo, const float* __restrict__ W1, const float* __restrict__ W2,
    unsigned short* __restrict__ ws) {
    int e = blockIdx.x * 256 + threadIdx.x;     // 0..655359
    int j, lane, kk, nt, n, k;
    float v;
    if (e < WS_O) {                             // QKV, K=256, 24 nt
        int t = e; j = t & 7; lane = (t >> 3) & 63; int r2 = t >> 9;
        kk = r2 & 7; nt = r2 >> 3;
        n = nt * 16 + (lane & 15); k = kk * 32 + (lane >> 4) * 8 + j;
        const float* W = (n < 128) ? Wq : ((n < 256) ? Wk : Wv);
        v = W[k * HD + (n & 127)];
    } else if (e < WS_1) {                      // Wo, K=128, 16 nt
        int t = e - WS_O; j = t & 7; lane = (t >> 3) & 63; int r2 = t >> 9;
        kk = r2 & 3; nt = r2 >> 2;
        n = nt * 16 + (lane & 15); k = kk * 32 + (lane >> 4) * 8 + j;
        v = Wo[k * EMB + n];
    } else if (e < WS_2) {                      // W1, K=256, 64 nt
        int t = e - WS_1; j = t & 7; lane = (t >> 3) & 63; int r2 = t >> 9;
        kk = r2 & 7; nt = r2 >> 3;
        n = nt * 16 + (lane & 15); k = kk * 32 + (lane >> 4) * 8 + j;
        v = W1[k * FF + n];
    } else {                                    // W2, K=1024, 16 nt
        int t = e - WS_2; j = t & 7; lane = (t >> 3) & 63; int r2 = t >> 9;
        kk = r2 & 31; nt = r2 >> 5;
        n = nt * 16 + (lane & 15); k = kk * 32 + (lane >> 4) * 8 + j;
        v = W2[k * EMB + n];
    }
    ws[e] = f32_to_bf16(v);
}

// one block = 4 sequences (M=128 rows). 4 waves. 160KB LDS -> 1 block/CU,
// so VGPR budget is 512/wave (launch_bounds min 1 wave/EU) -> no spills.
// B-weight fragments read ~once per block -> 4x arithmetic intensity vs M=32.
__global__ __launch_bounds__(256, 1) void attn_block_mfma(
    const float* __restrict__ X, const float* __restrict__ ln_g, const float* __restrict__ ln_b,
    const float* __restrict__ bq, const float* __restrict__ bk, const float* __restrict__ bv,
    const float* __restrict__ bo, const float* __restrict__ b1, const float* __restrict__ b2,
    const unsigned short* __restrict__ ws, float* __restrict__ out) {
    // LDS map (160KB):
    //   hbuf [128][256] b16 rb512 @0      (h after LN1; h2 after LN2)      64KB
    //   Qb   [128][128] b16 rb256 @64K    (Q; ctx after attn; fch in FFN)  32KB
    //   KVb  K,V [128][128] rb256 @96K    (X1 [128][256] rb512 after P4)   64KB
    __shared__ __attribute__((aligned(16))) char smem[163840];
    unsigned short* hbuf = (unsigned short*)smem;
    unsigned short* Qb   = (unsigned short*)(smem + 65536);
    char* Kc             = smem + 98304;
    char* Vc             = smem + 131072;
    unsigned short* X1b  = (unsigned short*)(smem + 98304);   // overlays K|V
    unsigned short* fch  = Qb;                                 // overlays Q/ctx

    const unsigned short* WTqkv = ws + WS_QKV;
    const unsigned short* WTo   = ws + WS_O;
    const unsigned short* WT1   = ws + WS_1;
    const unsigned short* WT2   = ws + WS_2;

    const int tid  = threadIdx.x;
    const int wv   = tid >> 6;
    const int lane = tid & 63;
    const int lr   = lane & 15;
    const int lh   = lane >> 4;
    const int row0 = blockIdx.x * M;            // global row base (4 seqs)
    const f32x4 Z  = {0.f, 0.f, 0.f, 0.f};

    // ---- P1: LN1 directly from global X -> hbuf (bf16, swz). 8 thr/row, 4 passes ----
    {
        const int r = tid >> 3, sub = tid & 7;
        #pragma unroll 1
        for (int pass = 0; pass < 4; ++pass) {
            int rr = pass * 32 + r;
            const float* xr = X + (size_t)(row0 + rr) * EMB;
            float4 vv[8];
            float s = 0.f, ss = 0.f;
            #pragma unroll
            for (int j = 0; j < 8; ++j) {
                float4 v = *(const float4*)&xr[sub * 4 + j * 32];
                vv[j] = v;
                s  += (v.x + v.y) + (v.z + v.w);
                ss += (v.x * v.x + v.y * v.y) + (v.z * v.z + v.w * v.w);
            }
            #pragma unroll
            for (int w = 1; w < 8; w <<= 1) { s += __shfl_xor(s, w, 64); ss += __shfl_xor(ss, w, 64); }
            float mu  = s * (1.f / EMB);
            float inv = rsqrtf(fmaxf(ss * (1.f / EMB) - mu * mu, 0.f) + EPSV);
            #pragma unroll
            for (int j = 0; j < 8; ++j) {
                int c = sub * 4 + j * 32;
                float4 v = vv[j];
                float4 g4 = *(const float4*)&ln_g[c];
                float4 b4 = *(const float4*)&ln_b[c];
                u16x4 pk;
                pk[0] = f32_to_bf16((v.x - mu) * inv * g4.x + b4.x);
                pk[1] = f32_to_bf16((v.y - mu) * inv * g4.y + b4.y);
                pk[2] = f32_to_bf16((v.z - mu) * inv * g4.z + b4.z);
                pk[3] = f32_to_bf16((v.w - mu) * inv * g4.w + b4.w);
                *(u16x4*)((char*)hbuf + ((rr * 512 + c * 2) ^ swzB(rr))) = pk;
            }
        }
    }
    __syncthreads();

    // ---- P2: QKV = h @ Wqkv + b.  wave owns 6 nt (of 24) x all 8 mt.  B 2x ----
    {
        #pragma unroll 1
        for (int mtp = 0; mtp < 8; mtp += 4) {
            u16x8 afr[4][8];
            #pragma unroll
            for (int m = 0; m < 4; ++m)
                #pragma unroll
                for (int kk = 0; kk < 8; ++kk)
                    afr[m][kk] = ldsA512(hbuf, (mtp + m) * 16 + lr, kk * 32 + lh * 8);
            #pragma unroll 2
            for (int i = 0; i < 6; ++i) {
                int nt = wv * 6 + i;
                u16x8 bfr[8];
                #pragma unroll
                for (int kk = 0; kk < 8; ++kk) bfr[kk] = ldgF(WTqkv, nt * 8 + kk, lane);
                int gcol = nt * 16 + lr;
                int mat = gcol >> 7, c = gcol & 127;
                const float* bias = (mat == 0) ? bq : ((mat == 1) ? bk : bv);
                float bc = bias[c];
                char* regbase = smem + 65536 + mat * 32768;
                #pragma unroll
                for (int m = 0; m < 4; ++m) {
                    f32x4 e = Z, o = Z;
                    #pragma unroll
                    for (int kk = 0; kk < 8; kk += 2) {
                        e = mfma16(afr[m][kk], bfr[kk], e);
                        o = mfma16(afr[m][kk + 1], bfr[kk + 1], o);
                    }
                    f32x4 a = e + o;
                    #pragma unroll
                    for (int reg = 0; reg < 4; ++reg) {
                        int r0 = (mtp + m) * 16 + lh * 4 + reg;
                        *(unsigned short*)(regbase + ((r0 * 256 + c * 2) ^ swzB(r0))) =
                            f32_to_bf16(a[reg] + bc);
                    }
                }
            }
        }
    }
    __syncthreads();

    // ---- P3: attention (VALU). thread=(head,q), 4 seqs serial. ctx -> Qb ----
    {
        const int hd = (tid >> 5) & 7, q = tid & 31;
        #pragma unroll 1
        for (int s = 0; s < 4; ++s) {
            int row = s * 32 + q;
            int by0 = (row * 256 + hd * 32) ^ swzB(row);
            int by1 = (row * 256 + hd * 32 + 16) ^ swzB(row);
            float qreg[16];
            {
                u16x8 a = *(const u16x8*)((const char*)Qb + by0);
                u16x8 b_ = *(const u16x8*)((const char*)Qb + by1);
                #pragma unroll
                for (int j = 0; j < 8; ++j) { qreg[j] = bf16_to_f32(a[j]); qreg[8 + j] = bf16_to_f32(b_[j]); }
            }
            float p[32]; float mmax = -1e30f;
            #pragma unroll
            for (int k = 0; k < 32; ++k) {
                int rk = s * 32 + k;
                int kb0 = (rk * 256 + hd * 32) ^ swzB(rk);
                int kb1 = (rk * 256 + hd * 32 + 16) ^ swzB(rk);
                u16x8 a = *(const u16x8*)(Kc + kb0);
                u16x8 b_ = *(const u16x8*)(Kc + kb1);
                float s_ = 0.f;
                #pragma unroll
                for (int j = 0; j < 8; ++j)
                    s_ += qreg[j] * bf16_to_f32(a[j]) + qreg[8 + j] * bf16_to_f32(b_[j]);
                s_ *= 0.25f;
                p[k] = s_;
                if (k <= q) mmax = fmaxf(mmax, s_);
            }
            float den = 0.f;
            #pragma unroll
            for (int k = 0; k < 32; ++k) {
                float e = (k <= q) ? __expf(p[k] - mmax) : 0.f;
                p[k] = e; den += e;
            }
            float rd = 1.f / den;
            float ctx[16];
            #pragma unroll
            for (int j = 0; j < 16; ++j) ctx[j] = 0.f;
            #pragma unroll
            for (int k = 0; k < 32; ++k) {
                int rk = s * 32 + k;
                int vb0 = (rk * 256 + hd * 32) ^ swzB(rk);
                int vb1 = (rk * 256 + hd * 32 + 16) ^ swzB(rk);
                u16x8 a = *(const u16x8*)(Vc + vb0);
                u16x8 b_ = *(const u16x8*)(Vc + vb1);
                float pk_ = p[k];
                #pragma unroll
                for (int j = 0; j < 8; ++j) { ctx[j] += pk_ * bf16_to_f32(a[j]); ctx[8 + j] += pk_ * bf16_to_f32(b_[j]); }
            }
            u16x8 o0, o1;
            #pragma unroll
            for (int j = 0; j < 8; ++j) { o0[j] = f32_to_bf16(ctx[j] * rd); o1[j] = f32_to_bf16(ctx[8 + j] * rd); }
            *(u16x8*)((char*)Qb + by0) = o0;
            *(u16x8*)((char*)Qb + by1) = o1;
        }
    }
    __syncthreads();

    // ---- P4: X1 = ctx @ Wo + bo + X(reload global) -> X1b bf16 (overlay K|V) ----
    {
        u16x8 afr[8][4];
        #pragma unroll
        for (int mt = 0; mt < 8; ++mt)
            #pragma unroll
            for (int kk = 0; kk < 4; ++kk)
                afr[mt][kk] = ldsA256(Qb, mt * 16 + lr, kk * 32 + lh * 8);
        #pragma unroll 2
        for (int i = 0; i < 4; ++i) {
            int nt = wv * 4 + i;
            u16x8 bfr[4];
            #pragma unroll
            for (int kk = 0; kk < 4; ++kk) bfr[kk] = ldgF(WTo, nt * 4 + kk, lane);
            int col = nt * 16 + lr;
            float bc = bo[col];
            #pragma unroll
            for (int mt = 0; mt < 8; ++mt) {
                f32x4 e = Z, o = Z;
                e = mfma16(afr[mt][0], bfr[0], e);
                o = mfma16(afr[mt][1], bfr[1], o);
                e = mfma16(afr[mt][2], bfr[2], e);
                o = mfma16(afr[mt][3], bfr[3], o);
                f32x4 a = e + o;
                #pragma unroll
                for (int reg = 0; reg < 4; ++reg) {
                    int r0 = mt * 16 + lh * 4 + reg;
                    float xv = X[(size_t)(row0 + r0) * EMB + col];
                    *(unsigned short*)((char*)X1b + ((r0 * 512 + col * 2) ^ swzB(r0))) =
                        f32_to_bf16(a[reg] + bc + xv);
                }
            }
        }
    }
    __syncthreads();

    // ---- P5: LN2 from X1b (bf16) -> hbuf ----
    {
        const int r = tid >> 3, sub = tid & 7;
        #pragma unroll 1
        for (int pass = 0; pass < 4; ++pass) {
            int rr = pass * 32 + r;
            float vals[32];
            float s = 0.f, ss = 0.f;
            #pragma unroll
            for (int j = 0; j < 8; ++j) {
                int c = sub * 4 + j * 32;
                u16x4 hv = *(const u16x4*)((const char*)X1b + ((rr * 512 + c * 2) ^ swzB(rr)));
                #pragma unroll
                for (int t = 0; t < 4; ++t) {
                    float f = bf16_to_f32(hv[t]);
                    vals[j * 4 + t] = f;
                    s += f; ss += f * f;
                }
            }
            #pragma unroll
            for (int w = 1; w < 8; w <<= 1) { s += __shfl_xor(s, w, 64); ss += __shfl_xor(ss, w, 64); }
            float mu  = s * (1.f / EMB);
            float inv = rsqrtf(fmaxf(ss * (1.f / EMB) - mu * mu, 0.f) + EPSV);
            #pragma unroll
            for (int j = 0; j < 8; ++j) {
                int c = sub * 4 + j * 32;
                float4 g4 = *(const float4*)&ln_g[c];
                float4 b4 = *(const float4*)&ln_b[c];
                u16x4 pk;
                pk[0] = f32_to_bf16((vals[j * 4 + 0] - mu) * inv * g4.x + b4.x);
                pk[1] = f32_to_bf16((vals[j * 4 + 1] - mu) * inv * g4.y + b4.y);
                pk[2] = f32_to_bf16((vals[j * 4 + 2] - mu) * inv * g4.z + b4.z);
                pk[3] = f32_to_bf16((vals[j * 4 + 3] - mu) * inv * g4.w + b4.w);
                *(u16x4*)((char*)hbuf + ((rr * 512 + c * 2) ^ swzB(rr))) = pk;
            }
        }
    }
    __syncthreads();

    // ---- P6: FFN in 8 chunks of 128 FF cols. fch overlays Q. acc2 persistent ----
    {
        f32x4 acc2[8][4];
        #pragma unroll
        for (int mt = 0; mt < 8; ++mt)
            #pragma unroll
            for (int i = 0; i < 4; ++i) acc2[mt][i] = Z;

        #pragma unroll 1
        for (int ch = 0; ch < 8; ++ch) {
            // FFN1: relu(h2 @ W1[:, chunk] + b1) -> fch.  wave owns 2 fn of 8.
            u16x8 bAll[2][8];
            #pragma unroll
            for (int f = 0; f < 2; ++f)
                #pragma unroll
                for (int kk = 0; kk < 8; ++kk)
                    bAll[f][kk] = ldgF(WT1, (ch * 8 + wv * 2 + f) * 8 + kk, lane);
            #pragma unroll 1
            for (int mtp = 0; mtp < 8; mtp += 2) {
                u16x8 afr[2][8];
                #pragma unroll
                for (int m = 0; m < 2; ++m)
                    #pragma unroll
                    for (int kk = 0; kk < 8; ++kk)
                        afr[m][kk] = ldsA512(hbuf, (mtp + m) * 16 + lr, kk * 32 + lh * 8);
                #pragma unroll
                for (int f = 0; f < 2; ++f) {
                    int fn = ch * 8 + wv * 2 + f;
                    float bc = b1[fn * 16 + lr];
                    int cc = (wv * 2 + f) * 16 + lr;
                    #pragma unroll
                    for (int m = 0; m < 2; ++m) {
                        f32x4 e = Z, o = Z;
                        #pragma unroll
                        for (int kk = 0; kk < 8; kk += 2) {
                            e = mfma16(afr[m][kk], bAll[f][kk], e);
                            o = mfma16(afr[m][kk + 1], bAll[f][kk + 1], o);
                        }
                        f32x4 a = e + o;
                        #pragma unroll
                        for (int reg = 0; reg < 4; ++reg) {
                            int r0 = (mtp + m) * 16 + lh * 4 + reg;
                            *(unsigned short*)((char*)fch + ((r0 * 256 + cc * 2) ^ swzB(r0))) =
                                f32_to_bf16(fmaxf(a[reg] + bc, 0.f));
                        }
                    }
                }
            }
            __syncthreads();
            // FFN2: acc2 += fch @ W2[chunk-slice].  wave owns 4 nt of 16; B 1x.
            u16x8 b2f[4][4];
            #pragma unroll
            for (int i = 0; i < 4; ++i)
                #pragma unroll
                for (int kk = 0; kk < 4; ++kk)
                    b2f[i][kk] = ldgF(WT2, (wv * 4 + i) * 32 + ch * 4 + kk, lane);
            #pragma unroll
            for (int mt = 0; mt < 8; ++mt) {
                u16x8 afr[4];
                #pragma unroll
                for (int kk = 0; kk < 4; ++kk)
                    afr[kk] = ldsA256(fch, mt * 16 + lr, kk * 32 + lh * 8);
                #pragma unroll
                for (int i = 0; i < 4; ++i) {
                    f32x4 t = acc2[mt][i];
                    t = mfma16(afr[0], b2f[i][0], t);
                    t = mfma16(afr[1], b2f[i][1], t);
                    t = mfma16(afr[2], b2f[i][2], t);
                    t = mfma16(afr[3], b2f[i][3], t);
                    acc2[mt][i] = t;
                }
            }
            __syncthreads();
        }
        // epilogue: out = acc2 + b2 + X1 (from LDS bf16)
        float* outp = out + (size_t)row0 * EMB;
        #pragma unroll
        for (int i = 0; i < 4; ++i) {
            int col = (wv * 4 + i) * 16 + lr;
            float bc = b2[col];
            #pragma unroll
            for (int mt = 0; mt < 8; ++mt) {
                #pragma unroll
                for (int reg = 0; reg < 4; ++reg) {
                    int r0 = mt * 16 + lh * 4 + reg;
                    float x1 = bf16_to_f32(*(const unsigned short*)((const char*)X1b +
                                          ((r0 * 512 + col * 2) ^ swzB(r0))));
                    outp[(size_t)r0 * EMB + col] = acc2[mt][i][reg] + bc + x1;
                }
            }
        }
    }
}

extern "C" void kernel_launch(void* const* d_in, const int* in_sizes, int n_in,
                              void* d_out, int out_size, void* d_ws, size_t ws_size,
                              hipStream_t stream) {
    const float* X    = (const float*)d_in[0];
    const float* ln_g = (const float*)d_in[1];
    const float* ln_b = (const float*)d_in[2];
    const float* Wq   = (const float*)d_in[3];
    const float* bq   = (const float*)d_in[4];
    const float* Wk   = (const float*)d_in[5];
    const float* bk   = (const float*)d_in[6];
    const float* Wv   = (const float*)d_in[7];
    const float* bv   = (const float*)d_in[8];
    const float* Wo   = (const float*)d_in[9];
    const float* bo   = (const float*)d_in[10];
    const float* W1   = (const float*)d_in[11];
    const float* b1   = (const float*)d_in[12];
    const float* W2   = (const float*)d_in[13];
    const float* b2   = (const float*)d_in[14];
    unsigned short* ws = (unsigned short*)d_ws;
    float* O = (float*)d_out;

    wconv<<<2560, 256, 0, stream>>>(Wq, Wk, Wv, Wo, W1, W2, ws);
    attn_block_mfma<<<1024, 256, 0, stream>>>(X, ln_g, ln_b, bq, bk, bv, bo, b1, b2, ws, O);
}